// Round 4
// baseline (461.338 us; speedup 1.0000x reference)
//
#include <hip/hip_runtime.h>

// PointNet++ set abstraction: ball query (first-16-by-index within r=0.5) +
// gather + rel-coords/feat concat + 2-layer MLP (leaky 0.1) + max-pool.
// B=4, N=16384, M=4096, K=16.
//
// Round 3: kill the pre-pass overhead (was ~110us of serialized dispatches).
//  - 3 dispatches total: pack -> build_lists -> persistent main.
//  - 2-priority work list (long scans first), dynamic per-wave work queue.
//  - Scan double-buffers 256-pt chunks: prefetch next chunk's 4 float4
//    before processing current -> hides L2 latency on straggler waves.
//  - d2 boundary semantics identical to the passing round-1/2 kernels.

constexpr int N_PTS = 16384;
constexpr int M_Q   = 4096;
constexpr int KNN   = 16;
constexpr int TOTAL_Q = 4 * M_Q;     // 16384
constexpr int TOTAL_P = 4 * N_PTS;   // 65536

// ---- ws layout ----
constexpr size_t WS_PKX   = 0;                               // float4[65536]
constexpr size_t WS_PKF   = WS_PKX + (size_t)TOTAL_P * 16;   // float4[65536]
constexpr size_t WS_LONG  = WS_PKF + (size_t)TOTAL_P * 16;   // int[16384]
constexpr size_t WS_SHORT = WS_LONG + (size_t)TOTAL_Q * 4;   // int[16384]
constexpr size_t WS_CNTS  = WS_SHORT + (size_t)TOTAL_Q * 4;  // int[2]
constexpr size_t WS_WCTR  = WS_CNTS + 64;                    // int[1]
constexpr size_t WS_NEED  = WS_WCTR + 64;

// ---------------- pre-pass A: pack points + zero counters ----------------
__global__ __launch_bounds__(256) void pack_kernel(
    const float* __restrict__ xyz, const float* __restrict__ feat,
    float4* __restrict__ pkX, float4* __restrict__ pkF,
    int* __restrict__ cnts, int* __restrict__ workCtr)
{
    const int i = blockIdx.x * 256 + threadIdx.x;
    if (i == 0) { cnts[0] = 0; cnts[1] = 0; *workCtr = 0; }
    if (i >= TOTAL_P) return;
    const float x = xyz[i * 3 + 0], y = xyz[i * 3 + 1], z = xyz[i * 3 + 2];
    // EXACT same expression as reference sum(p**2): rn mul/add, left-assoc.
    const float sq = __fadd_rn(__fadd_rn(__fmul_rn(x, x), __fmul_rn(y, y)),
                               __fmul_rn(z, z));
    pkX[i] = make_float4(x, y, z, sq);
    pkF[i] = make_float4(feat[i * 3 + 0], feat[i * 3 + 1], feat[i * 3 + 2], 0.0f);
}

// ---------------- pre-pass B: 2-priority lists ----------------
// Long-scan queries (|q|^2 > 5.5 => expected hits < ~26 => near-full scan)
// go in the long list; order within a list is irrelevant.
__global__ __launch_bounds__(256) void build_lists_kernel(
    const int* __restrict__ fps, const float4* __restrict__ pkX,
    int* __restrict__ longL, int* __restrict__ shortL, int* __restrict__ cnts)
{
    const int q = blockIdx.x * 256 + threadIdx.x;
    if (q >= TOTAL_Q) return;
    const int b = q >> 12;
    const float sq = pkX[b * N_PTS + fps[q]].w;
    if (sq > 5.5f) { longL[atomicAdd(&cnts[0], 1)] = q; }
    else           { shortL[atomicAdd(&cnts[1], 1)] = q; }
}

// ---------------- main persistent fused kernel ----------------
__global__ __launch_bounds__(256) void pe_flow_main_kernel(
    const float4* __restrict__ pkX, const float4* __restrict__ pkF,
    const int*   __restrict__ fps,
    const int*   __restrict__ longL, const int* __restrict__ shortL,
    const int*   __restrict__ cnts,  int* __restrict__ workCtr,
    const float* __restrict__ W1, const float* __restrict__ b1,
    const float* __restrict__ W2, const float* __restrict__ b2,
    float* __restrict__ out)
{
    __shared__ float sW1[192];
    __shared__ float sW2[1024];
    __shared__ float sb1[32];
    __shared__ float sb2[32];
    __shared__ int   sNbr[4][KNN];

    const int tid = threadIdx.x;
    if (tid < 192) sW1[tid] = W1[tid];
    for (int i = tid; i < 1024; i += 256) sW2[i] = W2[i];
    if (tid < 32) { sb1[tid] = b1[tid]; sb2[tid] = b2[tid]; }
    __syncthreads();

    const int wave = tid >> 6;
    const int lane = tid & 63;
    const unsigned long long lt_mask = (1ull << lane) - 1ull;
    const int nLong = cnts[0];

    for (;;) {
        // ---- pull next query (wave-uniform) ----
        int pos = 0;
        if (lane == 0) pos = atomicAdd(workCtr, 1);
        pos = __shfl(pos, 0, 64);
        if (pos >= TOTAL_Q) break;
        const int q = (pos < nLong) ? longL[pos] : shortL[pos - nLong];
        const int b = q >> 12;

        const float4* pX = pkX + (size_t)b * N_PTS;
        const float4* pF = pkF + (size_t)b * N_PTS;

        const int pidx = fps[q];
        const float4 Q = pX[pidx];
        const float qx = Q.x, qy = Q.y, qz = Q.z, sqq = Q.w;

        // ---- ball query: first 16 in-radius indices, ascending ----
        // Double-buffered 256-pt chunks: prefetch next before processing.
        int count = 0;
        float4 p[4], n[4];
        #pragma unroll
        for (int j = 0; j < 4; ++j) p[j] = pX[j * 64 + lane];

        for (int base = 0; base < N_PTS; base += 256) {
            const int nb = (base + 256 < N_PTS) ? base + 256 : base;
            #pragma unroll
            for (int j = 0; j < 4; ++j) n[j] = pX[nb + j * 64 + lane];

            #pragma unroll
            for (int j = 0; j < 4; ++j) {
                // dot as ascending FMA chain; d2 = (sqq+sqp) - 2*dot. Exact.
                float dot = __fmul_rn(qx, p[j].x);
                dot = __builtin_fmaf(qy, p[j].y, dot);
                dot = __builtin_fmaf(qz, p[j].z, dot);
                const float d2 = __fsub_rn(__fadd_rn(sqq, p[j].w),
                                           __fmul_rn(2.0f, dot));
                const bool hit = (d2 <= 0.25f);
                const unsigned long long mk = __ballot(hit);
                if (hit) {
                    const int ppos = count + __popcll(mk & lt_mask);
                    if (ppos < KNN) sNbr[wave][ppos] = base + j * 64 + lane;
                }
                count += (int)__popcll(mk);
            }
            if (count >= KNN) break;   // wave-uniform
            #pragma unroll
            for (int j = 0; j < 4; ++j) p[j] = n[j];
        }
        if (count < KNN) {
            const int first = sNbr[wave][0];   // count >= 1 (query itself)
            if (lane >= count && lane < KNN) sNbr[wave][lane] = first;
        }

        // ---- fused MLP: 64 lanes = 16 neighbors x 4 channel-groups(8) ----
        const int k = lane >> 2;
        const int co = (lane & 3) * 8;
        const int ni = sNbr[wave][k];

        const float4 gx = pX[ni];
        const float4 gf = pF[ni];
        const float in0 = gx.x - qx;
        const float in1 = gx.y - qy;
        const float in2 = gx.z - qz;

        float h1[8];
        #pragma unroll
        for (int i = 0; i < 8; ++i) {
            float a = sb1[co + i];
            a += in0  * sW1[0 * 32 + co + i];
            a += in1  * sW1[1 * 32 + co + i];
            a += in2  * sW1[2 * 32 + co + i];
            a += gf.x * sW1[3 * 32 + co + i];
            a += gf.y * sW1[4 * 32 + co + i];
            a += gf.z * sW1[5 * 32 + co + i];
            h1[i] = (a >= 0.0f) ? a : 0.1f * a;
        }

        float h2[8];
        #pragma unroll
        for (int i = 0; i < 8; ++i) h2[i] = sb2[co + i];
        const int baseLane = lane & ~3;
        #pragma unroll
        for (int jj = 0; jj < 8; ++jj) {
            #pragma unroll
            for (int g = 0; g < 4; ++g) {
                const float v = __shfl(h1[jj], baseLane + g, 64);
                const int row = g * 8 + jj;
                #pragma unroll
                for (int i = 0; i < 8; ++i)
                    h2[i] += v * sW2[row * 32 + co + i];
            }
        }

        #pragma unroll
        for (int i = 0; i < 8; ++i) {
            float v = h2[i];
            v = (v >= 0.0f) ? v : 0.1f * v;
            v = fmaxf(v, __shfl_xor(v, 4, 64));
            v = fmaxf(v, __shfl_xor(v, 8, 64));
            v = fmaxf(v, __shfl_xor(v, 16, 64));
            v = fmaxf(v, __shfl_xor(v, 32, 64));
            h2[i] = v;
        }

        if (k == 0) {
            float* op = out + (size_t)q * 32 + co;
            #pragma unroll
            for (int i = 0; i < 8; ++i) op[i] = h2[i];
        }
    }
}

// ---------------- round-1 fallback (self-contained, proven PASS) ----------------
__global__ __launch_bounds__(256) void pe_flow_fused_kernel(
    const float* __restrict__ xyz, const float* __restrict__ feat,
    const int* __restrict__ fps,
    const float* __restrict__ W1, const float* __restrict__ b1,
    const float* __restrict__ W2, const float* __restrict__ b2,
    float* __restrict__ out)
{
    __shared__ float sW1[192];
    __shared__ float sW2[1024];
    __shared__ float sb1[32];
    __shared__ float sb2[32];
    __shared__ int   sNbr[4][KNN];

    const int tid = threadIdx.x;
    if (tid < 192) sW1[tid] = W1[tid];
    for (int i = tid; i < 1024; i += 256) sW2[i] = W2[i];
    if (tid < 32) { sb1[tid] = b1[tid]; sb2[tid] = b2[tid]; }
    __syncthreads();

    const int wave = tid >> 6;
    const int lane = tid & 63;
    const int q = blockIdx.x * 4 + wave;
    const int b = q >> 12;
    const int m = q & (M_Q - 1);

    const float* xb = xyz  + (size_t)b * N_PTS * 3;
    const float* fb = feat + (size_t)b * N_PTS * 3;

    const int pidx = fps[b * M_Q + m];
    const float qx = xb[pidx * 3 + 0];
    const float qy = xb[pidx * 3 + 1];
    const float qz = xb[pidx * 3 + 2];
    const float sq_q = __fadd_rn(__fadd_rn(__fmul_rn(qx, qx), __fmul_rn(qy, qy)),
                                 __fmul_rn(qz, qz));

    int count = 0;
    const unsigned long long lt_mask = (1ull << lane) - 1ull;
    for (int base = 0; base < N_PTS; base += 64) {
        const int i = base + lane;
        const float px = xb[i * 3 + 0];
        const float py = xb[i * 3 + 1];
        const float pz = xb[i * 3 + 2];
        const float sq_p = __fadd_rn(__fadd_rn(__fmul_rn(px, px), __fmul_rn(py, py)),
                                     __fmul_rn(pz, pz));
        float dot = __fmul_rn(qx, px);
        dot = __builtin_fmaf(qy, py, dot);
        dot = __builtin_fmaf(qz, pz, dot);
        const float d2 = __fsub_rn(__fadd_rn(sq_q, sq_p), __fmul_rn(2.0f, dot));
        const bool hit = (d2 <= 0.25f);
        const unsigned long long mk = __ballot(hit);
        if (hit) {
            const int pos = count + __popcll(mk & lt_mask);
            if (pos < KNN) sNbr[wave][pos] = i;
        }
        count += (int)__popcll(mk);
        if (count >= KNN) break;
    }
    if (count < KNN) {
        const int first = sNbr[wave][0];
        if (lane >= count && lane < KNN) sNbr[wave][lane] = first;
    }

    const int k = lane >> 2;
    const int co = (lane & 3) * 8;
    const int ni = sNbr[wave][k];

    const float in0 = xb[ni * 3 + 0] - qx;
    const float in1 = xb[ni * 3 + 1] - qy;
    const float in2 = xb[ni * 3 + 2] - qz;
    const float in3 = fb[ni * 3 + 0];
    const float in4 = fb[ni * 3 + 1];
    const float in5 = fb[ni * 3 + 2];

    float h1[8];
    #pragma unroll
    for (int i = 0; i < 8; ++i) {
        float a = sb1[co + i];
        a += in0 * sW1[0 * 32 + co + i];
        a += in1 * sW1[1 * 32 + co + i];
        a += in2 * sW1[2 * 32 + co + i];
        a += in3 * sW1[3 * 32 + co + i];
        a += in4 * sW1[4 * 32 + co + i];
        a += in5 * sW1[5 * 32 + co + i];
        h1[i] = (a >= 0.0f) ? a : 0.1f * a;
    }

    float h2[8];
    #pragma unroll
    for (int i = 0; i < 8; ++i) h2[i] = sb2[co + i];
    const int baseLane = lane & ~3;
    #pragma unroll
    for (int jj = 0; jj < 8; ++jj) {
        #pragma unroll
        for (int g = 0; g < 4; ++g) {
            const float v = __shfl(h1[jj], baseLane + g, 64);
            const int row = g * 8 + jj;
            #pragma unroll
            for (int i = 0; i < 8; ++i)
                h2[i] += v * sW2[row * 32 + co + i];
        }
    }

    #pragma unroll
    for (int i = 0; i < 8; ++i) {
        float v = h2[i];
        v = (v >= 0.0f) ? v : 0.1f * v;
        v = fmaxf(v, __shfl_xor(v, 4, 64));
        v = fmaxf(v, __shfl_xor(v, 8, 64));
        v = fmaxf(v, __shfl_xor(v, 16, 64));
        v = fmaxf(v, __shfl_xor(v, 32, 64));
        h2[i] = v;
    }

    if (k == 0) {
        float* op = out + (size_t)q * 32 + co;
        #pragma unroll
        for (int i = 0; i < 8; ++i) op[i] = h2[i];
    }
}

extern "C" void kernel_launch(void* const* d_in, const int* in_sizes, int n_in,
                              void* d_out, int out_size, void* d_ws, size_t ws_size,
                              hipStream_t stream) {
    const float* xyz  = (const float*)d_in[0];
    const float* feat = (const float*)d_in[1];
    const int*   fps  = (const int*)d_in[2];
    const float* W1   = (const float*)d_in[3];
    const float* b1   = (const float*)d_in[4];
    const float* W2   = (const float*)d_in[5];
    const float* b2   = (const float*)d_in[6];
    float* out = (float*)d_out;

    if (ws_size < WS_NEED) {
        // fallback: proven round-1 kernel, no workspace needed
        pe_flow_fused_kernel<<<TOTAL_Q / 4, 256, 0, stream>>>(
            xyz, feat, fps, W1, b1, W2, b2, out);
        return;
    }

    char* ws = (char*)d_ws;
    float4* pkX = (float4*)(ws + WS_PKX);
    float4* pkF = (float4*)(ws + WS_PKF);
    int* longL   = (int*)(ws + WS_LONG);
    int* shortL  = (int*)(ws + WS_SHORT);
    int* cnts    = (int*)(ws + WS_CNTS);
    int* workCtr = (int*)(ws + WS_WCTR);

    pack_kernel<<<TOTAL_P / 256, 256, 0, stream>>>(xyz, feat, pkX, pkF, cnts, workCtr);
    build_lists_kernel<<<TOTAL_Q / 256, 256, 0, stream>>>(fps, pkX, longL, shortL, cnts);
    pe_flow_main_kernel<<<2048, 256, 0, stream>>>(
        pkX, pkF, fps, longL, shortL, cnts, workCtr, W1, b1, W2, b2, out);
}

// Round 5
// 81.273 us; speedup vs baseline: 5.6764x; 5.6764x over previous
//
#include <hip/hip_runtime.h>

// PointNet++ set abstraction: ball query (first-16-by-index within r=0.5) +
// gather + rel-coords/feat concat + 2-layer MLP (leaky 0.1) + max-pool.
// B=4, N=16384, M=4096, K=16.
//
// Round 5: round-3's proven main structure (static assignment, 69.7us) +
// cheap pre-pass:
//  - ONE pre-kernel: packs float4 points AND builds long/short query lists
//    with wave-aggregated atomics (1 ballot + 1 atomicAdd per wave per list;
//    round-4 lesson: per-thread same-address atomics serialize ~10ns each).
//  - Main kernel: static q from lists (long scans first), 8 float4 loads in
//    flight per 512-pt chunk, NO dynamic queue, NO register double-buffer.
//  - d2 boundary semantics identical to the passing round-1/2/3 kernels.

constexpr int N_PTS = 16384;
constexpr int M_Q   = 4096;
constexpr int KNN   = 16;
constexpr int TOTAL_Q = 4 * M_Q;     // 16384
constexpr int TOTAL_P = 4 * N_PTS;   // 65536

// ---- ws layout ----
constexpr size_t WS_PKX   = 0;                               // float4[65536]
constexpr size_t WS_PKF   = WS_PKX + (size_t)TOTAL_P * 16;   // float4[65536]
constexpr size_t WS_LONG  = WS_PKF + (size_t)TOTAL_P * 16;   // int[16384]
constexpr size_t WS_SHORT = WS_LONG + (size_t)TOTAL_Q * 4;   // int[16384]
constexpr size_t WS_CNTS  = WS_SHORT + (size_t)TOTAL_Q * 4;  // int[2]
constexpr size_t WS_NEED  = WS_CNTS + 64;

// ------- pre-pass: pack points + build 2-priority query lists -------
__global__ __launch_bounds__(256) void prep_kernel(
    const float* __restrict__ xyz, const float* __restrict__ feat,
    const int* __restrict__ fps,
    float4* __restrict__ pkX, float4* __restrict__ pkF,
    int* __restrict__ longL, int* __restrict__ shortL, int* __restrict__ cnts)
{
    const int i = blockIdx.x * 256 + threadIdx.x;
    const int lane = threadIdx.x & 63;
    const unsigned long long lt_mask = (1ull << lane) - 1ull;

    // pack points: {x,y,z,|p|^2} with the reference-exact sq expression
    if (i < TOTAL_P) {
        const float x = xyz[i * 3 + 0], y = xyz[i * 3 + 1], z = xyz[i * 3 + 2];
        const float sq = __fadd_rn(__fadd_rn(__fmul_rn(x, x), __fmul_rn(y, y)),
                                   __fmul_rn(z, z));
        pkX[i] = make_float4(x, y, z, sq);
        pkF[i] = make_float4(feat[i * 3 + 0], feat[i * 3 + 1], feat[i * 3 + 2], 0.0f);
    }

    // classify queries (first 16384 threads = 256 full waves)
    if (i < TOTAL_Q) {
        const int q = i;
        const int b = q >> 12;
        const int pidx = fps[q];
        const size_t base3 = ((size_t)b * N_PTS + pidx) * 3;
        const float x = xyz[base3 + 0], y = xyz[base3 + 1], z = xyz[base3 + 2];
        const float sq = __fadd_rn(__fadd_rn(__fmul_rn(x, x), __fmul_rn(y, y)),
                                   __fmul_rn(z, z));
        const bool isLong = (sq > 5.5f);   // expected hits < ~30 => near-full scan

        // wave-aggregated append to longL
        const unsigned long long mkL = __ballot(isLong);
        int baseL = 0;
        if (lane == 0 && mkL) baseL = atomicAdd(&cnts[0], (int)__popcll(mkL));
        baseL = __shfl(baseL, 0, 64);
        if (isLong) longL[baseL + __popcll(mkL & lt_mask)] = q;

        // wave-aggregated append to shortL
        const unsigned long long mkS = ~mkL;   // full wave: complement
        int baseS = 0;
        if (lane == 0 && mkS) baseS = atomicAdd(&cnts[1], (int)__popcll(mkS));
        baseS = __shfl(baseS, 0, 64);
        if (!isLong) shortL[baseS + __popcll(mkS & lt_mask)] = q;
    }
}

// ---------------- main fused kernel (static assignment) ----------------
__global__ __launch_bounds__(256) void pe_flow_main_kernel(
    const float4* __restrict__ pkX, const float4* __restrict__ pkF,
    const int*   __restrict__ fps,
    const int*   __restrict__ longL, const int* __restrict__ shortL,
    const int*   __restrict__ cnts,
    const float* __restrict__ W1, const float* __restrict__ b1,
    const float* __restrict__ W2, const float* __restrict__ b2,
    float* __restrict__ out)
{
    __shared__ float sW1[192];
    __shared__ float sW2[1024];
    __shared__ float sb1[32];
    __shared__ float sb2[32];
    __shared__ int   sNbr[4][KNN];

    const int tid = threadIdx.x;
    if (tid < 192) sW1[tid] = W1[tid];
    for (int i = tid; i < 1024; i += 256) sW2[i] = W2[i];
    if (tid < 32) { sb1[tid] = b1[tid]; sb2[tid] = b2[tid]; }
    __syncthreads();

    const int wave = tid >> 6;
    const int lane = tid & 63;
    const unsigned long long lt_mask = (1ull << lane) - 1ull;

    const int w = blockIdx.x * 4 + wave;        // 0..16383, long-first order
    const int nLong = cnts[0];
    const int q = (w < nLong) ? longL[w] : shortL[w - nLong];
    const int b = q >> 12;

    const float4* pX = pkX + (size_t)b * N_PTS;
    const float4* pF = pkF + (size_t)b * N_PTS;

    const int pidx = fps[q];
    const float4 Q = pX[pidx];
    const float qx = Q.x, qy = Q.y, qz = Q.z, sqq = Q.w;

    // ---- ball query: first 16 in-radius indices, ascending ----
    // 512 points per iteration: 8 float4 loads in flight per lane.
    int count = 0;
    for (int base = 0; base < N_PTS; base += 512) {
        float4 p[8];
        #pragma unroll
        for (int j = 0; j < 8; ++j) p[j] = pX[base + j * 64 + lane];
        #pragma unroll
        for (int j = 0; j < 8; ++j) {
            // dot as ascending FMA chain; d2 = (sqq+sqp) - 2*dot. Exact.
            float dot = __fmul_rn(qx, p[j].x);
            dot = __builtin_fmaf(qy, p[j].y, dot);
            dot = __builtin_fmaf(qz, p[j].z, dot);
            const float d2 = __fsub_rn(__fadd_rn(sqq, p[j].w),
                                       __fmul_rn(2.0f, dot));
            const bool hit = (d2 <= 0.25f);
            const unsigned long long mk = __ballot(hit);
            if (hit) {
                const int pos = count + __popcll(mk & lt_mask);
                if (pos < KNN) sNbr[wave][pos] = base + j * 64 + lane;
            }
            count += (int)__popcll(mk);
        }
        if (count >= KNN) break;   // wave-uniform
    }
    if (count < KNN) {
        const int first = sNbr[wave][0];   // count >= 1 (query point itself)
        if (lane >= count && lane < KNN) sNbr[wave][lane] = first;
    }

    // ---- fused MLP: 64 lanes = 16 neighbors x 4 channel-groups(8) ----
    const int k = lane >> 2;
    const int co = (lane & 3) * 8;
    const int ni = sNbr[wave][k];

    const float4 gx = pX[ni];
    const float4 gf = pF[ni];
    const float in0 = gx.x - qx;
    const float in1 = gx.y - qy;
    const float in2 = gx.z - qz;

    float h1[8];
    #pragma unroll
    for (int i = 0; i < 8; ++i) {
        float a = sb1[co + i];
        a += in0  * sW1[0 * 32 + co + i];
        a += in1  * sW1[1 * 32 + co + i];
        a += in2  * sW1[2 * 32 + co + i];
        a += gf.x * sW1[3 * 32 + co + i];
        a += gf.y * sW1[4 * 32 + co + i];
        a += gf.z * sW1[5 * 32 + co + i];
        h1[i] = (a >= 0.0f) ? a : 0.1f * a;
    }

    float h2[8];
    #pragma unroll
    for (int i = 0; i < 8; ++i) h2[i] = sb2[co + i];
    const int baseLane = lane & ~3;
    #pragma unroll
    for (int jj = 0; jj < 8; ++jj) {
        #pragma unroll
        for (int g = 0; g < 4; ++g) {
            const float v = __shfl(h1[jj], baseLane + g, 64);
            const int row = g * 8 + jj;
            #pragma unroll
            for (int i = 0; i < 8; ++i)
                h2[i] += v * sW2[row * 32 + co + i];
        }
    }

    #pragma unroll
    for (int i = 0; i < 8; ++i) {
        float v = h2[i];
        v = (v >= 0.0f) ? v : 0.1f * v;
        v = fmaxf(v, __shfl_xor(v, 4, 64));
        v = fmaxf(v, __shfl_xor(v, 8, 64));
        v = fmaxf(v, __shfl_xor(v, 16, 64));
        v = fmaxf(v, __shfl_xor(v, 32, 64));
        h2[i] = v;
    }

    if (k == 0) {
        float* op = out + (size_t)q * 32 + co;
        #pragma unroll
        for (int i = 0; i < 8; ++i) op[i] = h2[i];
    }
}

// ---------------- round-1 fallback (self-contained, proven PASS) ----------------
__global__ __launch_bounds__(256) void pe_flow_fused_kernel(
    const float* __restrict__ xyz, const float* __restrict__ feat,
    const int* __restrict__ fps,
    const float* __restrict__ W1, const float* __restrict__ b1,
    const float* __restrict__ W2, const float* __restrict__ b2,
    float* __restrict__ out)
{
    __shared__ float sW1[192];
    __shared__ float sW2[1024];
    __shared__ float sb1[32];
    __shared__ float sb2[32];
    __shared__ int   sNbr[4][KNN];

    const int tid = threadIdx.x;
    if (tid < 192) sW1[tid] = W1[tid];
    for (int i = tid; i < 1024; i += 256) sW2[i] = W2[i];
    if (tid < 32) { sb1[tid] = b1[tid]; sb2[tid] = b2[tid]; }
    __syncthreads();

    const int wave = tid >> 6;
    const int lane = tid & 63;
    const int q = blockIdx.x * 4 + wave;
    const int b = q >> 12;
    const int m = q & (M_Q - 1);

    const float* xb = xyz  + (size_t)b * N_PTS * 3;
    const float* fb = feat + (size_t)b * N_PTS * 3;

    const int pidx = fps[b * M_Q + m];
    const float qx = xb[pidx * 3 + 0];
    const float qy = xb[pidx * 3 + 1];
    const float qz = xb[pidx * 3 + 2];
    const float sq_q = __fadd_rn(__fadd_rn(__fmul_rn(qx, qx), __fmul_rn(qy, qy)),
                                 __fmul_rn(qz, qz));

    int count = 0;
    const unsigned long long lt_mask = (1ull << lane) - 1ull;
    for (int base = 0; base < N_PTS; base += 64) {
        const int i = base + lane;
        const float px = xb[i * 3 + 0];
        const float py = xb[i * 3 + 1];
        const float pz = xb[i * 3 + 2];
        const float sq_p = __fadd_rn(__fadd_rn(__fmul_rn(px, px), __fmul_rn(py, py)),
                                     __fmul_rn(pz, pz));
        float dot = __fmul_rn(qx, px);
        dot = __builtin_fmaf(qy, py, dot);
        dot = __builtin_fmaf(qz, pz, dot);
        const float d2 = __fsub_rn(__fadd_rn(sq_q, sq_p), __fmul_rn(2.0f, dot));
        const bool hit = (d2 <= 0.25f);
        const unsigned long long mk = __ballot(hit);
        if (hit) {
            const int pos = count + __popcll(mk & lt_mask);
            if (pos < KNN) sNbr[wave][pos] = i;
        }
        count += (int)__popcll(mk);
        if (count >= KNN) break;
    }
    if (count < KNN) {
        const int first = sNbr[wave][0];
        if (lane >= count && lane < KNN) sNbr[wave][lane] = first;
    }

    const int k = lane >> 2;
    const int co = (lane & 3) * 8;
    const int ni = sNbr[wave][k];

    const float in0 = xb[ni * 3 + 0] - qx;
    const float in1 = xb[ni * 3 + 1] - qy;
    const float in2 = xb[ni * 3 + 2] - qz;
    const float in3 = fb[ni * 3 + 0];
    const float in4 = fb[ni * 3 + 1];
    const float in5 = fb[ni * 3 + 2];

    float h1[8];
    #pragma unroll
    for (int i = 0; i < 8; ++i) {
        float a = sb1[co + i];
        a += in0 * sW1[0 * 32 + co + i];
        a += in1 * sW1[1 * 32 + co + i];
        a += in2 * sW1[2 * 32 + co + i];
        a += in3 * sW1[3 * 32 + co + i];
        a += in4 * sW1[4 * 32 + co + i];
        a += in5 * sW1[5 * 32 + co + i];
        h1[i] = (a >= 0.0f) ? a : 0.1f * a;
    }

    float h2[8];
    #pragma unroll
    for (int i = 0; i < 8; ++i) h2[i] = sb2[co + i];
    const int baseLane = lane & ~3;
    #pragma unroll
    for (int jj = 0; jj < 8; ++jj) {
        #pragma unroll
        for (int g = 0; g < 4; ++g) {
            const float v = __shfl(h1[jj], baseLane + g, 64);
            const int row = g * 8 + jj;
            #pragma unroll
            for (int i = 0; i < 8; ++i)
                h2[i] += v * sW2[row * 32 + co + i];
        }
    }

    #pragma unroll
    for (int i = 0; i < 8; ++i) {
        float v = h2[i];
        v = (v >= 0.0f) ? v : 0.1f * v;
        v = fmaxf(v, __shfl_xor(v, 4, 64));
        v = fmaxf(v, __shfl_xor(v, 8, 64));
        v = fmaxf(v, __shfl_xor(v, 16, 64));
        v = fmaxf(v, __shfl_xor(v, 32, 64));
        h2[i] = v;
    }

    if (k == 0) {
        float* op = out + (size_t)q * 32 + co;
        #pragma unroll
        for (int i = 0; i < 8; ++i) op[i] = h2[i];
    }
}

extern "C" void kernel_launch(void* const* d_in, const int* in_sizes, int n_in,
                              void* d_out, int out_size, void* d_ws, size_t ws_size,
                              hipStream_t stream) {
    const float* xyz  = (const float*)d_in[0];
    const float* feat = (const float*)d_in[1];
    const int*   fps  = (const int*)d_in[2];
    const float* W1   = (const float*)d_in[3];
    const float* b1   = (const float*)d_in[4];
    const float* W2   = (const float*)d_in[5];
    const float* b2   = (const float*)d_in[6];
    float* out = (float*)d_out;

    if (ws_size < WS_NEED) {
        // fallback: proven round-1 kernel, no workspace needed
        pe_flow_fused_kernel<<<TOTAL_Q / 4, 256, 0, stream>>>(
            xyz, feat, fps, W1, b1, W2, b2, out);
        return;
    }

    char* ws = (char*)d_ws;
    float4* pkX  = (float4*)(ws + WS_PKX);
    float4* pkF  = (float4*)(ws + WS_PKF);
    int* longL   = (int*)(ws + WS_LONG);
    int* shortL  = (int*)(ws + WS_SHORT);
    int* cnts    = (int*)(ws + WS_CNTS);

    hipMemsetAsync(cnts, 0, 8, stream);
    prep_kernel<<<TOTAL_P / 256, 256, 0, stream>>>(
        xyz, feat, fps, pkX, pkF, longL, shortL, cnts);
    pe_flow_main_kernel<<<TOTAL_Q / 4, 256, 0, stream>>>(
        pkX, pkF, fps, longL, shortL, cnts, W1, b1, W2, b2, out);
}

// Round 6
// 72.300 us; speedup vs baseline: 6.3809x; 1.1241x over previous
//
#include <hip/hip_runtime.h>

// PointNet++ set abstraction: ball query (first-16-by-index within r=0.5) +
// gather + rel-coords/feat concat + 2-layer MLP (leaky 0.1) + max-pool.
// B=4, N=16384, M=4096, K=16.
//
// Round 6: break the per-chunk load-latency chain.
//  - Two register banks, 1024 pts/iter: load B -> proc A -> load A' -> proc B.
//    No register copies (round-3 lesson), no dynamic queue (round-4 lesson).
//  - sched_barrier(0) after each 8-load batch pins loads above compute so
//    they issue 8-in-flight instead of being sunk to first use.
//  - 4 walking pointers so every load is reg+imm (j*1024 <= 3072 bytes).
//  - prep/pre-pass identical to proven round-5 (wave-aggregated atomics).
//  - d2 boundary semantics identical to the passing round-1/2/3/5 kernels.

constexpr int N_PTS = 16384;
constexpr int M_Q   = 4096;
constexpr int KNN   = 16;
constexpr int TOTAL_Q = 4 * M_Q;     // 16384
constexpr int TOTAL_P = 4 * N_PTS;   // 65536

// ---- ws layout ----
constexpr size_t WS_PKX   = 0;                               // float4[65536]
constexpr size_t WS_PKF   = WS_PKX + (size_t)TOTAL_P * 16;   // float4[65536]
constexpr size_t WS_LONG  = WS_PKF + (size_t)TOTAL_P * 16;   // int[16384]
constexpr size_t WS_SHORT = WS_LONG + (size_t)TOTAL_Q * 4;   // int[16384]
constexpr size_t WS_CNTS  = WS_SHORT + (size_t)TOTAL_Q * 4;  // int[2]
constexpr size_t WS_NEED  = WS_CNTS + 64;

// ------- pre-pass: pack points + build 2-priority query lists -------
__global__ __launch_bounds__(256) void prep_kernel(
    const float* __restrict__ xyz, const float* __restrict__ feat,
    const int* __restrict__ fps,
    float4* __restrict__ pkX, float4* __restrict__ pkF,
    int* __restrict__ longL, int* __restrict__ shortL, int* __restrict__ cnts)
{
    const int i = blockIdx.x * 256 + threadIdx.x;
    const int lane = threadIdx.x & 63;
    const unsigned long long lt_mask = (1ull << lane) - 1ull;

    // pack points: {x,y,z,|p|^2} with the reference-exact sq expression
    if (i < TOTAL_P) {
        const float x = xyz[i * 3 + 0], y = xyz[i * 3 + 1], z = xyz[i * 3 + 2];
        const float sq = __fadd_rn(__fadd_rn(__fmul_rn(x, x), __fmul_rn(y, y)),
                                   __fmul_rn(z, z));
        pkX[i] = make_float4(x, y, z, sq);
        pkF[i] = make_float4(feat[i * 3 + 0], feat[i * 3 + 1], feat[i * 3 + 2], 0.0f);
    }

    // classify queries (first 16384 threads = 256 full waves)
    if (i < TOTAL_Q) {
        const int q = i;
        const int b = q >> 12;
        const int pidx = fps[q];
        const size_t base3 = ((size_t)b * N_PTS + pidx) * 3;
        const float x = xyz[base3 + 0], y = xyz[base3 + 1], z = xyz[base3 + 2];
        const float sq = __fadd_rn(__fadd_rn(__fmul_rn(x, x), __fmul_rn(y, y)),
                                   __fmul_rn(z, z));
        const bool isLong = (sq > 5.5f);

        const unsigned long long mkL = __ballot(isLong);
        int baseL = 0;
        if (lane == 0 && mkL) baseL = atomicAdd(&cnts[0], (int)__popcll(mkL));
        baseL = __shfl(baseL, 0, 64);
        if (isLong) longL[baseL + __popcll(mkL & lt_mask)] = q;

        const unsigned long long mkS = ~mkL;
        int baseS = 0;
        if (lane == 0 && mkS) baseS = atomicAdd(&cnts[1], (int)__popcll(mkS));
        baseS = __shfl(baseS, 0, 64);
        if (!isLong) shortL[baseS + __popcll(mkS & lt_mask)] = q;
    }
}

// ---------------- main fused kernel ----------------
#define LOAD8(R, P, P2)                                          \
    {                                                            \
        _Pragma("unroll")                                        \
        for (int j = 0; j < 4; ++j) R[j] = (P)[j * 64];          \
        _Pragma("unroll")                                        \
        for (int j = 0; j < 4; ++j) R[4 + j] = (P2)[j * 64];     \
    }

#define PROC8(R, CB)                                                          \
    {                                                                         \
        _Pragma("unroll")                                                     \
        for (int j = 0; j < 8; ++j) {                                         \
            float dot = __fmul_rn(qx, R[j].x);                                \
            dot = __builtin_fmaf(qy, R[j].y, dot);                            \
            dot = __builtin_fmaf(qz, R[j].z, dot);                            \
            const float d2 = __fsub_rn(__fadd_rn(sqq, R[j].w),                \
                                       __fmul_rn(2.0f, dot));                 \
            const bool hit = (d2 <= 0.25f);                                   \
            const unsigned long long mk = __ballot(hit);                      \
            if (hit) {                                                        \
                const int pos = count + __popcll(mk & lt_mask);               \
                if (pos < KNN) sNbr[wave][pos] = (CB) + j * 64 + lane;        \
            }                                                                 \
            count += (int)__popcll(mk);                                       \
        }                                                                     \
    }

__global__ __launch_bounds__(256) void pe_flow_main_kernel(
    const float4* __restrict__ pkX, const float4* __restrict__ pkF,
    const int*   __restrict__ fps,
    const int*   __restrict__ longL, const int* __restrict__ shortL,
    const int*   __restrict__ cnts,
    const float* __restrict__ W1, const float* __restrict__ b1,
    const float* __restrict__ W2, const float* __restrict__ b2,
    float* __restrict__ out)
{
    __shared__ float sW1[192];
    __shared__ float sW2[1024];
    __shared__ float sb1[32];
    __shared__ float sb2[32];
    __shared__ int   sNbr[4][KNN];

    const int tid = threadIdx.x;
    if (tid < 192) sW1[tid] = W1[tid];
    for (int i = tid; i < 1024; i += 256) sW2[i] = W2[i];
    if (tid < 32) { sb1[tid] = b1[tid]; sb2[tid] = b2[tid]; }
    __syncthreads();

    const int wave = tid >> 6;
    const int lane = tid & 63;
    const unsigned long long lt_mask = (1ull << lane) - 1ull;

    const int w = blockIdx.x * 4 + wave;        // 0..16383, long-first order
    const int nLong = cnts[0];
    const int q = (w < nLong) ? longL[w] : shortL[w - nLong];
    const int b = q >> 12;

    const float4* pX = pkX + (size_t)b * N_PTS;
    const float4* pF = pkF + (size_t)b * N_PTS;

    const int pidx = fps[q];
    const float4 Q = pX[pidx];
    const float qx = Q.x, qy = Q.y, qz = Q.z, sqq = Q.w;

    // ---- ball query: first 16 in-radius indices, ascending ----
    // Two register banks of 8 float4 (512 pts each); prefetch across banks.
    int count = 0;
    {
        const float4* pA  = pX + lane;          // chunk A base
        const float4* pA2 = pA + 256;
        const float4* pB  = pA + 512;           // chunk B base
        const float4* pB2 = pA + 768;
        float4 ra[8], rb[8];

        LOAD8(ra, pA, pA2);
        __builtin_amdgcn_sched_barrier(0);

        for (int base = 0; base < N_PTS; base += 1024) {
            LOAD8(rb, pB, pB2);                 // B in flight over proc A
            __builtin_amdgcn_sched_barrier(0);
            PROC8(ra, base);
            if (count >= KNN) break;            // wave-uniform

            pA += 1024; pA2 += 1024;
            if (base + 1024 < N_PTS) {          // uniform guard, no OOB
                LOAD8(ra, pA, pA2);             // next A over proc B
                __builtin_amdgcn_sched_barrier(0);
            }
            PROC8(rb, base + 512);
            if (count >= KNN) break;            // wave-uniform
            pB += 1024; pB2 += 1024;
        }
    }
    if (count < KNN) {
        const int first = sNbr[wave][0];   // count >= 1 (query point itself)
        if (lane >= count && lane < KNN) sNbr[wave][lane] = first;
    }

    // ---- fused MLP: 64 lanes = 16 neighbors x 4 channel-groups(8) ----
    const int k = lane >> 2;
    const int co = (lane & 3) * 8;
    const int ni = sNbr[wave][k];

    const float4 gx = pX[ni];
    const float4 gf = pF[ni];
    const float in0 = gx.x - qx;
    const float in1 = gx.y - qy;
    const float in2 = gx.z - qz;

    float h1[8];
    #pragma unroll
    for (int i = 0; i < 8; ++i) {
        float a = sb1[co + i];
        a += in0  * sW1[0 * 32 + co + i];
        a += in1  * sW1[1 * 32 + co + i];
        a += in2  * sW1[2 * 32 + co + i];
        a += gf.x * sW1[3 * 32 + co + i];
        a += gf.y * sW1[4 * 32 + co + i];
        a += gf.z * sW1[5 * 32 + co + i];
        h1[i] = (a >= 0.0f) ? a : 0.1f * a;
    }

    float h2[8];
    #pragma unroll
    for (int i = 0; i < 8; ++i) h2[i] = sb2[co + i];
    const int baseLane = lane & ~3;
    #pragma unroll
    for (int jj = 0; jj < 8; ++jj) {
        #pragma unroll
        for (int g = 0; g < 4; ++g) {
            const float v = __shfl(h1[jj], baseLane + g, 64);
            const int row = g * 8 + jj;
            #pragma unroll
            for (int i = 0; i < 8; ++i)
                h2[i] += v * sW2[row * 32 + co + i];
        }
    }

    #pragma unroll
    for (int i = 0; i < 8; ++i) {
        float v = h2[i];
        v = (v >= 0.0f) ? v : 0.1f * v;
        v = fmaxf(v, __shfl_xor(v, 4, 64));
        v = fmaxf(v, __shfl_xor(v, 8, 64));
        v = fmaxf(v, __shfl_xor(v, 16, 64));
        v = fmaxf(v, __shfl_xor(v, 32, 64));
        h2[i] = v;
    }

    if (k == 0) {
        float* op = out + (size_t)q * 32 + co;
        #pragma unroll
        for (int i = 0; i < 8; ++i) op[i] = h2[i];
    }
}

// ---------------- round-1 fallback (self-contained, proven PASS) ----------------
__global__ __launch_bounds__(256) void pe_flow_fused_kernel(
    const float* __restrict__ xyz, const float* __restrict__ feat,
    const int* __restrict__ fps,
    const float* __restrict__ W1, const float* __restrict__ b1,
    const float* __restrict__ W2, const float* __restrict__ b2,
    float* __restrict__ out)
{
    __shared__ float sW1[192];
    __shared__ float sW2[1024];
    __shared__ float sb1[32];
    __shared__ float sb2[32];
    __shared__ int   sNbr[4][KNN];

    const int tid = threadIdx.x;
    if (tid < 192) sW1[tid] = W1[tid];
    for (int i = tid; i < 1024; i += 256) sW2[i] = W2[i];
    if (tid < 32) { sb1[tid] = b1[tid]; sb2[tid] = b2[tid]; }
    __syncthreads();

    const int wave = tid >> 6;
    const int lane = tid & 63;
    const int q = blockIdx.x * 4 + wave;
    const int b = q >> 12;
    const int m = q & (M_Q - 1);

    const float* xb = xyz  + (size_t)b * N_PTS * 3;
    const float* fb = feat + (size_t)b * N_PTS * 3;

    const int pidx = fps[b * M_Q + m];
    const float qx = xb[pidx * 3 + 0];
    const float qy = xb[pidx * 3 + 1];
    const float qz = xb[pidx * 3 + 2];
    const float sq_q = __fadd_rn(__fadd_rn(__fmul_rn(qx, qx), __fmul_rn(qy, qy)),
                                 __fmul_rn(qz, qz));

    int count = 0;
    const unsigned long long lt_mask = (1ull << lane) - 1ull;
    for (int base = 0; base < N_PTS; base += 64) {
        const int i = base + lane;
        const float px = xb[i * 3 + 0];
        const float py = xb[i * 3 + 1];
        const float pz = xb[i * 3 + 2];
        const float sq_p = __fadd_rn(__fadd_rn(__fmul_rn(px, px), __fmul_rn(py, py)),
                                     __fmul_rn(pz, pz));
        float dot = __fmul_rn(qx, px);
        dot = __builtin_fmaf(qy, py, dot);
        dot = __builtin_fmaf(qz, pz, dot);
        const float d2 = __fsub_rn(__fadd_rn(sq_q, sq_p), __fmul_rn(2.0f, dot));
        const bool hit = (d2 <= 0.25f);
        const unsigned long long mk = __ballot(hit);
        if (hit) {
            const int pos = count + __popcll(mk & lt_mask);
            if (pos < KNN) sNbr[wave][pos] = i;
        }
        count += (int)__popcll(mk);
        if (count >= KNN) break;
    }
    if (count < KNN) {
        const int first = sNbr[wave][0];
        if (lane >= count && lane < KNN) sNbr[wave][lane] = first;
    }

    const int k = lane >> 2;
    const int co = (lane & 3) * 8;
    const int ni = sNbr[wave][k];

    const float in0 = xb[ni * 3 + 0] - qx;
    const float in1 = xb[ni * 3 + 1] - qy;
    const float in2 = xb[ni * 3 + 2] - qz;
    const float in3 = fb[ni * 3 + 0];
    const float in4 = fb[ni * 3 + 1];
    const float in5 = fb[ni * 3 + 2];

    float h1[8];
    #pragma unroll
    for (int i = 0; i < 8; ++i) {
        float a = sb1[co + i];
        a += in0 * sW1[0 * 32 + co + i];
        a += in1 * sW1[1 * 32 + co + i];
        a += in2 * sW1[2 * 32 + co + i];
        a += in3 * sW1[3 * 32 + co + i];
        a += in4 * sW1[4 * 32 + co + i];
        a += in5 * sW1[5 * 32 + co + i];
        h1[i] = (a >= 0.0f) ? a : 0.1f * a;
    }

    float h2[8];
    #pragma unroll
    for (int i = 0; i < 8; ++i) h2[i] = sb2[co + i];
    const int baseLane = lane & ~3;
    #pragma unroll
    for (int jj = 0; jj < 8; ++jj) {
        #pragma unroll
        for (int g = 0; g < 4; ++g) {
            const float v = __shfl(h1[jj], baseLane + g, 64);
            const int row = g * 8 + jj;
            #pragma unroll
            for (int i = 0; i < 8; ++i)
                h2[i] += v * sW2[row * 32 + co + i];
        }
    }

    #pragma unroll
    for (int i = 0; i < 8; ++i) {
        float v = h2[i];
        v = (v >= 0.0f) ? v : 0.1f * v;
        v = fmaxf(v, __shfl_xor(v, 4, 64));
        v = fmaxf(v, __shfl_xor(v, 8, 64));
        v = fmaxf(v, __shfl_xor(v, 16, 64));
        v = fmaxf(v, __shfl_xor(v, 32, 64));
        h2[i] = v;
    }

    if (k == 0) {
        float* op = out + (size_t)q * 32 + co;
        #pragma unroll
        for (int i = 0; i < 8; ++i) op[i] = h2[i];
    }
}

extern "C" void kernel_launch(void* const* d_in, const int* in_sizes, int n_in,
                              void* d_out, int out_size, void* d_ws, size_t ws_size,
                              hipStream_t stream) {
    const float* xyz  = (const float*)d_in[0];
    const float* feat = (const float*)d_in[1];
    const int*   fps  = (const int*)d_in[2];
    const float* W1   = (const float*)d_in[3];
    const float* b1   = (const float*)d_in[4];
    const float* W2   = (const float*)d_in[5];
    const float* b2   = (const float*)d_in[6];
    float* out = (float*)d_out;

    if (ws_size < WS_NEED) {
        // fallback: proven round-1 kernel, no workspace needed
        pe_flow_fused_kernel<<<TOTAL_Q / 4, 256, 0, stream>>>(
            xyz, feat, fps, W1, b1, W2, b2, out);
        return;
    }

    char* ws = (char*)d_ws;
    float4* pkX  = (float4*)(ws + WS_PKX);
    float4* pkF  = (float4*)(ws + WS_PKF);
    int* longL   = (int*)(ws + WS_LONG);
    int* shortL  = (int*)(ws + WS_SHORT);
    int* cnts    = (int*)(ws + WS_CNTS);

    hipMemsetAsync(cnts, 0, 8, stream);
    prep_kernel<<<TOTAL_P / 256, 256, 0, stream>>>(
        xyz, feat, fps, pkX, pkF, longL, shortL, cnts);
    pe_flow_main_kernel<<<TOTAL_Q / 4, 256, 0, stream>>>(
        pkX, pkF, fps, longL, shortL, cnts, W1, b1, W2, b2, out);
}